// Round 19
// baseline (1498.614 us; speedup 1.0000x reference)
//
#include <hip/hip_runtime.h>
#include <cstdint>

// Problem constants (fixed by setup_inputs()).
#define NLINKS 20000
#define NPATHS 20000
#define LSEQ   8
#define TITER  8
#define DD     64
#define GW     192          // 3*DD gate width
#define NEDGE  (NPATHS * LSEQ)        // 160000
#define NB     ((NPATHS + 63) / 64)   // 313 blocks of 64 rows

// Soft workgroup barrier: LDS-visibility only (lgkmcnt), NO vmcnt drain —
// global loads/stores stay in flight across it.
__device__ static inline void softbar() {
  asm volatile("s_waitcnt lgkmcnt(0)" ::: "memory");
  __builtin_amdgcn_s_barrier();
  asm volatile("" ::: "memory");
}

// ---------------- Threefry-2x32 (exact JAX semantics) ----------------
__host__ __device__ static inline uint32_t rotl32(uint32_t x, unsigned r) {
  return (x << r) | (x >> (32u - r));
}

__host__ __device__ static inline void threefry2x32(uint32_t k0, uint32_t k1,
                                                    uint32_t c0, uint32_t c1,
                                                    uint32_t& o0, uint32_t& o1) {
  uint32_t ks0 = k0, ks1 = k1, ks2 = k0 ^ k1 ^ 0x1BD11BDAu;
  uint32_t x0 = c0 + ks0, x1 = c1 + ks1;
#define TF_R(r) { x0 += x1; x1 = rotl32(x1, r); x1 ^= x0; }
  TF_R(13) TF_R(15) TF_R(26) TF_R(6)  x0 += ks1; x1 += ks2 + 1u;
  TF_R(17) TF_R(29) TF_R(16) TF_R(24) x0 += ks2; x1 += ks0 + 2u;
  TF_R(13) TF_R(15) TF_R(26) TF_R(6)  x0 += ks0; x1 += ks1 + 3u;
  TF_R(17) TF_R(29) TF_R(16) TF_R(24) x0 += ks1; x1 += ks2 + 4u;
  TF_R(13) TF_R(15) TF_R(26) TF_R(6)  x0 += ks2; x1 += ks0 + 5u;
#undef TF_R
  o0 = x0; o1 = x1;
}

// bernoulli(key, 0.5, (20000,256)), flattened element j.
// jax_threefry_partitionable=True: counter (0, j), bits = o0 ^ o1.
__device__ static inline bool bern_keep(uint32_t key0, uint32_t key1, uint32_t j) {
  uint32_t o0, o1;
  threefry2x32(key0, key1, 0u, j, o0, o1);
  uint32_t bits = o0 ^ o1;
  float u = __uint_as_float((bits >> 9) | 0x3f800000u) - 1.0f;
  return u < 0.5f;
}

// Fast gates: __expf -> v_exp_f32 (native); abs err ~1e-7 (verified round 18:
// absmax 1.2e-4 vs 3.05e-3 threshold).
__device__ static inline float sigmoidf_(float x) {
  return 1.0f / (1.0f + __expf(-x));
}
__device__ static inline float tanh_fast(float x) {
  return 2.0f * sigmoidf_(2.0f * x) - 1.0f;
}
__device__ static inline float seluf_(float x) {
  const float sc = 1.0507009873554805f;
  const float al = 1.6732632423543772f;
  return x > 0.0f ? sc * x : sc * al * expm1f(x);
}

// ---------------- init + CSR build (round-12 verified) ----------------
__global__ void init_gather_kernel(const float* __restrict__ cap,
                                   const float* __restrict__ traffic,
                                   float* __restrict__ link_state,
                                   float* __restrict__ seq_h,
                                   int* __restrict__ counts) {
  int i = blockIdx.x * blockDim.x + threadIdx.x;
  if (i < NLINKS * DD)
    link_state[i] = ((i & 63) == 0) ? cap[i >> 6] : 0.0f;
  if (i < NPATHS * DD) {
    int p = i >> 6, j = i & 63;
    seq_h[(p * LSEQ + (LSEQ - 1)) * DD + j] = (j == 0) ? traffic[p] : 0.0f;
  }
  if (i < NLINKS) counts[i] = 0;
}

__global__ void csr_hist_kernel(const int* __restrict__ links,
                                int* __restrict__ counts) {
  int e = blockIdx.x * blockDim.x + threadIdx.x;
  if (e < NEDGE) atomicAdd(&counts[links[e]], 1);
}

__global__ __launch_bounds__(1024, 1) void csr_scan_kernel(
    const int* __restrict__ counts,
    int* __restrict__ row_start,
    int* __restrict__ cursor) {
  __shared__ int sc[1024];
  const int i = threadIdx.x;
  const int base = i * 20;
  int s = 0;
  for (int j = 0; j < 20; ++j) {
    int r = base + j;
    if (r < NLINKS) s += counts[r];
  }
  sc[i] = s;
  __syncthreads();
  for (int off = 1; off < 1024; off <<= 1) {
    int v = (i >= off) ? sc[i - off] : 0;
    __syncthreads();
    sc[i] += v;
    __syncthreads();
  }
  int run = sc[i] - s;
  for (int j = 0; j < 20; ++j) {
    int r = base + j;
    if (r < NLINKS) {
      row_start[r] = run;
      cursor[r] = run;
      run += counts[r];
    }
  }
}

__global__ void csr_fill_kernel(const int* __restrict__ links,
                                int* __restrict__ cursor,
                                int* __restrict__ edges) {
  int e = blockIdx.x * blockDim.x + threadIdx.x;
  if (e < NEDGE) {
    int l = links[e];
    int pos = atomicAdd(&cursor[l], 1);
    edges[pos] = e;
  }
}

// ============================================================================
// gx (PACKED layout): slice w of link l = cols {8w..8w+8} U {128+4w..128+4w+4}
// stored contiguously at gx[l*192 + 12w .. +12).
// ============================================================================
__global__ __launch_bounds__(1024, 2) void gx_pack_kernel(
    const float* __restrict__ link_state,
    const float* __restrict__ Wx,
    const float* __restrict__ bias,
    float* __restrict__ gx) {
  __shared__ float ls_s[64][65];

  const int tid  = threadIdx.x;
  const int lane = tid & 63;
  const int w    = __builtin_amdgcn_readfirstlane(tid >> 6);   // 0..15
  const int l0   = blockIdx.x * 64;

  {
    int p = tid >> 4, c = tid & 15;
    int lr = min(l0 + p, NLINKS - 1);
    float4 v = reinterpret_cast<const float4*>(link_state)[lr * 16 + c];
    ls_s[p][c * 4 + 0] = v.x; ls_s[p][c * 4 + 1] = v.y;
    ls_s[p][c * 4 + 2] = v.z; ls_s[p][c * 4 + 3] = v.w;
  }

  const int gA = w * 8;
  const int gC = 128 + w * 4;
  float ga[12];
#pragma unroll
  for (int jj = 0; jj < 8; ++jj) ga[jj] = bias[gA + jj];
#pragma unroll
  for (int jj = 0; jj < 4; ++jj) ga[8 + jj] = bias[gC + jj];
  softbar();

#pragma unroll 4
  for (int k = 0; k < DD; ++k) {
    float xk = ls_s[lane][k];
    const float* wA = &Wx[k * GW + gA];   // wave-uniform -> s_load
    const float* wC = &Wx[k * GW + gC];
#pragma unroll
    for (int jj = 0; jj < 8; ++jj) ga[jj] = fmaf(xk, wA[jj], ga[jj]);
#pragma unroll
    for (int jj = 0; jj < 4; ++jj) ga[8 + jj] = fmaf(xk, wC[jj], ga[8 + jj]);
  }

  if (l0 + lane < NLINKS) {
    float* dst = &gx[(size_t)(l0 + lane) * GW + w * 12];
#pragma unroll
    for (int s = 0; s < 3; ++s)
      reinterpret_cast<float4*>(dst)[s] =
          make_float4(ga[s * 4 + 0], ga[s * 4 + 1], ga[s * 4 + 2], ga[s * 4 + 3]);
  }
}

// ============================================================================
// path GRU v16: k-blocked b128 LDS layout h4/z4/r4 [16][65][4] (padded ->
// conflict-light staging); strictly member-wise access on register float4s
// (NO reinterpret_cast on locals -> no scratch demotion; the rounds-14/15
// failure mode). h_old for own cols carried in registers; seq stores
// coalesced by (sp,sc) threads. Race structure identical to verified v13:
// all h4/z4/r4 reads pre-BAR1 or post-BAR1 matching their writes.
// Reference GRU (Python precedence): hh = tanh(xh + (r*h) @ Wh[:,2D:]).
// ============================================================================
__global__ __launch_bounds__(1024, 8) void path_gru_v16_kernel(
    const float* __restrict__ gx,
    float* __restrict__ seq_h,
    const int* __restrict__ links,
    const float* __restrict__ Wh) {
  __shared__ float h4[16][65][4];   // h4[kb][p][i] = h[p][4kb+i]
  __shared__ float z4[16][65][4];
  __shared__ float r4[16][65][4];   // rh

  const int tid  = threadIdx.x;
  const int lane = tid & 63;
  const int w    = __builtin_amdgcn_readfirstlane(tid >> 6);   // 0..15
  const int p0   = blockIdx.x * 64;

  const int ab0 = w * 8;          // gate col base: z for w<8, r for w>=8
  const int cc0 = 128 + w * 4;    // cand col base
  const int prow = min(p0 + lane, NPATHS - 1);
  const float4* gx4 = reinterpret_cast<const float4*>(gx);
  float4* seq4 = reinterpret_cast<float4*>(seq_h);

  const int sp = tid >> 4, sc = tid & 15;      // staging thread coords
  const int spr = min(p0 + sp, NPATHS - 1);
  const bool svalid = (p0 + sp) < NPATHS;

  // initial h: thread (sp,sc) loads seq row (coalesced) -> h4[sc][sp]
  {
    float4 v = seq4[(size_t)(spr * LSEQ + 7) * 16 + sc];
    *reinterpret_cast<float4*>(&h4[sc][sp][0]) = v;
  }

  // gathers for t=0: packed slice = 3 consecutive float4
  float4 gz0, gz1, gc0;
  {
    int li = links[prow * LSEQ + 0];
    const float4* g = gx4 + (size_t)li * 48 + w * 3;
    gz0 = g[0]; gz1 = g[1]; gc0 = g[2];
  }
  softbar();   // h4 staged

  // register copy of own h cols [4w, 4w+4)
  float4 hprev = *reinterpret_cast<const float4*>(&h4[w][lane][0]);

  for (int t = 0; t < LSEQ; ++t) {
    // store out(t-1): (sp,sc) reads h4[sc][sp] (b128) -> coalesced 256B/row.
    if (t > 0 && svalid) {
      float4 v = *reinterpret_cast<const float4*>(&h4[sc][sp][0]);
      seq4[(size_t)(spr * LSEQ + (t - 1)) * 16 + sc] = v;
    }

    // phase 1: aB = h @ Wh[:, ab0..ab0+8); h via 16 b128 reads
    float aB[8];
#pragma unroll
    for (int jj = 0; jj < 8; ++jj) aB[jj] = 0.0f;
#pragma unroll 4
    for (int kb = 0; kb < 16; ++kb) {
      float4 hv = *reinterpret_cast<const float4*>(&h4[kb][lane][0]);
      const float* w0 = &Wh[(4 * kb + 0) * GW + ab0];   // wave-uniform
      const float* w1 = &Wh[(4 * kb + 1) * GW + ab0];
      const float* w2 = &Wh[(4 * kb + 2) * GW + ab0];
      const float* w3 = &Wh[(4 * kb + 3) * GW + ab0];
#pragma unroll
      for (int jj = 0; jj < 8; ++jj) {
        aB[jj] = fmaf(hv.x, w0[jj], aB[jj]);
        aB[jj] = fmaf(hv.y, w1[jj], aB[jj]);
        aB[jj] = fmaf(hv.z, w2[jj], aB[jj]);
        aB[jj] = fmaf(hv.w, w3[jj], aB[jj]);
      }
    }

    // gate write (consumes gz; compiler places the vmcnt wait here)
    if (w < 8) {
      float s0 = sigmoidf_(gz0.x + aB[0]);
      float s1 = sigmoidf_(gz0.y + aB[1]);
      float s2 = sigmoidf_(gz0.z + aB[2]);
      float s3 = sigmoidf_(gz0.w + aB[3]);
      float s4 = sigmoidf_(gz1.x + aB[4]);
      float s5 = sigmoidf_(gz1.y + aB[5]);
      float s6 = sigmoidf_(gz1.z + aB[6]);
      float s7 = sigmoidf_(gz1.w + aB[7]);
      *reinterpret_cast<float4*>(&z4[2 * w][lane][0]) = make_float4(s0, s1, s2, s3);
      *reinterpret_cast<float4*>(&z4[2 * w + 1][lane][0]) = make_float4(s4, s5, s6, s7);
    } else {
      const int kb0 = 2 * (w - 8);
      float4 h0 = *reinterpret_cast<const float4*>(&h4[kb0][lane][0]);
      float4 h1 = *reinterpret_cast<const float4*>(&h4[kb0 + 1][lane][0]);
      float r0 = sigmoidf_(gz0.x + aB[0]) * h0.x;
      float r1 = sigmoidf_(gz0.y + aB[1]) * h0.y;
      float r2 = sigmoidf_(gz0.z + aB[2]) * h0.z;
      float r3 = sigmoidf_(gz0.w + aB[3]) * h0.w;
      float r4v = sigmoidf_(gz1.x + aB[4]) * h1.x;
      float r5 = sigmoidf_(gz1.y + aB[5]) * h1.y;
      float r6 = sigmoidf_(gz1.z + aB[6]) * h1.z;
      float r7 = sigmoidf_(gz1.w + aB[7]) * h1.w;
      *reinterpret_cast<float4*>(&r4[kb0][lane][0]) = make_float4(r0, r1, r2, r3);
      *reinterpret_cast<float4*>(&r4[kb0 + 1][lane][0]) = make_float4(r4v, r5, r6, r7);
    }
    softbar();  // BAR1: z/rh visible; all phase-1 h4 reads + seq-store reads done

    // phase 2
    int li_n = (t < LSEQ - 1) ? links[prow * LSEQ + t + 1] : 0;

    float aC[4];
#pragma unroll
    for (int jj = 0; jj < 4; ++jj) aC[jj] = 0.0f;
#pragma unroll 4
    for (int kb = 0; kb < 16; ++kb) {
      float4 rv = *reinterpret_cast<const float4*>(&r4[kb][lane][0]);
      const float* w0 = &Wh[(4 * kb + 0) * GW + cc0];   // wave-uniform
      const float* w1 = &Wh[(4 * kb + 1) * GW + cc0];
      const float* w2 = &Wh[(4 * kb + 2) * GW + cc0];
      const float* w3 = &Wh[(4 * kb + 3) * GW + cc0];
#pragma unroll
      for (int jj = 0; jj < 4; ++jj) {
        aC[jj] = fmaf(rv.x, w0[jj], aC[jj]);
        aC[jj] = fmaf(rv.y, w1[jj], aC[jj]);
        aC[jj] = fmaf(rv.z, w2[jj], aC[jj]);
        aC[jj] = fmaf(rv.w, w3[jj], aC[jj]);
      }
    }
    {
      float4 zv = *reinterpret_cast<const float4*>(&z4[w][lane][0]);
      float4 hn;
      hn.x = zv.x * hprev.x + (1.0f - zv.x) * tanh_fast(gc0.x + aC[0]);
      hn.y = zv.y * hprev.y + (1.0f - zv.y) * tanh_fast(gc0.y + aC[1]);
      hn.z = zv.z * hprev.z + (1.0f - zv.z) * tanh_fast(gc0.z + aC[2]);
      hn.w = zv.w * hprev.w + (1.0f - zv.w) * tanh_fast(gc0.w + aC[3]);
      *reinterpret_cast<float4*>(&h4[w][lane][0]) = hn;
      hprev = hn;
    }

    // issue gathers for t+1 AFTER last use of gz/gc; in flight across BAR2
    // + next phase 1 (soft barrier: no vmcnt drain).
    if (t < LSEQ - 1) {
      const float4* g = gx4 + (size_t)li_n * 48 + w * 3;
      gz0 = g[0]; gz1 = g[1]; gc0 = g[2];
    }
    softbar();  // BAR2: h4 updated; z4/r4 free
  }

  // final store: out(7) coalesced from h4
  if (svalid) {
    float4 v = *reinterpret_cast<const float4*>(&h4[sc][sp][0]);
    seq4[(size_t)(spr * LSEQ + 7) * 16 + sc] = v;
  }
}

// ============================================================================
// link GRU v11p (round-18 verified, unchanged): b32 state, native-exp gates,
// fused PACKED gx tail.
// ============================================================================
__global__ __launch_bounds__(1024, 8) void link_gru_v11_kernel(
    float* __restrict__ link_state,
    const float* __restrict__ seq_h,
    const int* __restrict__ row_start,
    const int* __restrict__ row_end,
    const int* __restrict__ edges,
    const float* __restrict__ Wx,
    const float* __restrict__ Wh,
    const float* __restrict__ bias,
    const float* __restrict__ pWx,
    const float* __restrict__ pb,
    float* __restrict__ gx_out) {
  __shared__ float h_s[64][65];
  __shared__ float x_s[64][65];
  __shared__ float r_s[64][65];

  const int tid  = threadIdx.x;
  const int lane = tid & 63;
  const int w    = __builtin_amdgcn_readfirstlane(tid >> 6);   // 0..15
  const int l0   = blockIdx.x * 64;

  {
    int p = tid >> 4, c = tid & 15;
    float4 hv = make_float4(0.f, 0.f, 0.f, 0.f);
    float4 xv = make_float4(0.f, 0.f, 0.f, 0.f);
    if (l0 + p < NLINKS) {
      hv = reinterpret_cast<const float4*>(link_state)[(l0 + p) * 16 + c];
      const float4* s4 = reinterpret_cast<const float4*>(seq_h);
      int rs = row_start[l0 + p], re = row_end[l0 + p];
      int ii = rs;
      for (; ii + 4 <= re; ii += 4) {
        int e0 = edges[ii + 0], e1 = edges[ii + 1];
        int e2 = edges[ii + 2], e3 = edges[ii + 3];
        float4 v0 = s4[e0 * 16 + c], v1 = s4[e1 * 16 + c];
        float4 v2 = s4[e2 * 16 + c], v3 = s4[e3 * 16 + c];
        xv.x += v0.x + v1.x + v2.x + v3.x;
        xv.y += v0.y + v1.y + v2.y + v3.y;
        xv.z += v0.z + v1.z + v2.z + v3.z;
        xv.w += v0.w + v1.w + v2.w + v3.w;
      }
      for (; ii < re; ++ii) {
        int e = edges[ii];
        float4 v = s4[e * 16 + c];
        xv.x += v.x; xv.y += v.y; xv.z += v.z; xv.w += v.w;
      }
    }
    h_s[p][c * 4 + 0] = hv.x; h_s[p][c * 4 + 1] = hv.y;
    h_s[p][c * 4 + 2] = hv.z; h_s[p][c * 4 + 3] = hv.w;
    x_s[p][c * 4 + 0] = xv.x; x_s[p][c * 4 + 1] = xv.y;
    x_s[p][c * 4 + 2] = xv.z; x_s[p][c * 4 + 3] = xv.w;
  }

  const int ab0 = w * 8;
  const int cc0 = 128 + w * 4;
  const int hc0 = w * 4;

  float bab[8], bcc[4];
#pragma unroll
  for (int jj = 0; jj < 8; ++jj) bab[jj] = bias[ab0 + jj];
#pragma unroll
  for (int jj = 0; jj < 4; ++jj) bcc[jj] = bias[cc0 + jj];

  softbar();

  float aA[8], aB[8], cA[4];
#pragma unroll
  for (int jj = 0; jj < 8; ++jj) { aA[jj] = bab[jj]; aB[jj] = 0.0f; }
#pragma unroll
  for (int jj = 0; jj < 4; ++jj) cA[jj] = bcc[jj];
#pragma unroll 4
  for (int k = 0; k < DD; ++k) {
    float xk = x_s[lane][k];
    float hk = h_s[lane][k];
    const float* wxp = &Wx[k * GW + ab0];   // wave-uniform -> s_load
    const float* whp = &Wh[k * GW + ab0];
    const float* wxc = &Wx[k * GW + cc0];
#pragma unroll
    for (int jj = 0; jj < 8; ++jj) {
      aA[jj] = fmaf(xk, wxp[jj], aA[jj]);
      aB[jj] = fmaf(hk, whp[jj], aB[jj]);
    }
#pragma unroll
    for (int jj = 0; jj < 4; ++jj)
      cA[jj] = fmaf(xk, wxc[jj], cA[jj]);
  }
  softbar();  // all waves' x_s reads complete before z overwrites x_s

  if (w < 8) {
#pragma unroll
    for (int jj = 0; jj < 8; ++jj)
      x_s[lane][ab0 + jj] = sigmoidf_(aA[jj] + aB[jj]);   // z (reuse x_s)
  } else {
#pragma unroll
    for (int jj = 0; jj < 8; ++jj) {
      int hj = ab0 - 64 + jj;
      float r = sigmoidf_(aA[jj] + aB[jj]);
      r_s[lane][hj] = r * h_s[lane][hj];
    }
  }
  softbar();

  float aC[4];
#pragma unroll
  for (int jj = 0; jj < 4; ++jj) aC[jj] = 0.0f;
#pragma unroll 4
  for (int k = 0; k < DD; ++k) {
    float rhk = r_s[lane][k];
    const float* whc = &Wh[k * GW + cc0];   // wave-uniform -> s_load
#pragma unroll
    for (int jj = 0; jj < 4; ++jj)
      aC[jj] = fmaf(rhk, whc[jj], aC[jj]);
  }
  {
    float o[4];
#pragma unroll
    for (int jj = 0; jj < 4; ++jj) {
      int j = hc0 + jj;
      float z    = x_s[lane][j];
      float hold = h_s[lane][j];
      float hh = tanh_fast(cA[jj] + aC[jj]);
      o[jj] = z * hold + (1.0f - z) * hh;
      x_s[lane][j] = o[jj];    // own-wave col: z read above, now h_new
    }
    if (l0 + lane < NLINKS) {
      reinterpret_cast<float4*>(&link_state[(size_t)(l0 + lane) * DD + hc0])[0]
          = make_float4(o[0], o[1], o[2], o[3]);
    }
  }
  softbar();  // h_new (all 64 cols) visible in x_s

  {
    const int gA = w * 8;
    const int gC = 128 + w * 4;
    float ga[12];
#pragma unroll
    for (int jj = 0; jj < 8; ++jj) ga[jj] = pb[gA + jj];
#pragma unroll
    for (int jj = 0; jj < 4; ++jj) ga[8 + jj] = pb[gC + jj];
#pragma unroll 4
    for (int k = 0; k < DD; ++k) {
      float hk = x_s[lane][k];
      const float* wA = &pWx[k * GW + gA];   // wave-uniform -> s_load
      const float* wC = &pWx[k * GW + gC];
#pragma unroll
      for (int jj = 0; jj < 8; ++jj) ga[jj] = fmaf(hk, wA[jj], ga[jj]);
#pragma unroll
      for (int jj = 0; jj < 4; ++jj) ga[8 + jj] = fmaf(hk, wC[jj], ga[8 + jj]);
    }
    if (l0 + lane < NLINKS) {
      float* dst = &gx_out[(size_t)(l0 + lane) * GW + w * 12];
#pragma unroll
      for (int s = 0; s < 3; ++s)
        reinterpret_cast<float4*>(dst)[s] =
            make_float4(ga[s * 4 + 0], ga[s * 4 + 1], ga[s * 4 + 2], ga[s * 4 + 3]);
    }
  }
}

// ============================================================================
// MLP v9 (round-12 verified): ps overlay in hbuf, 70 KB LDS -> 2 blocks/CU.
// ============================================================================
__global__ __launch_bounds__(1024, 8) void mlp_v9_kernel(
    const float4* __restrict__ ps4, int rs4,
    const float* __restrict__ W1, const float* __restrict__ b1,
    const float* __restrict__ W2, const float* __restrict__ b2,
    const float* __restrict__ W3, const float* __restrict__ b3,
    float* __restrict__ out,
    uint32_t k1a, uint32_t k1b, uint32_t k2a, uint32_t k2b) {
  __shared__ float hraw[64 * 257];
  __shared__ float part_s[64][17];

  const int tid  = threadIdx.x;
  const int lane = tid & 63;
  const int w    = __builtin_amdgcn_readfirstlane(tid >> 6);   // 0..15
  const int p0   = blockIdx.x * 64;
  const int c0   = w * 16;

  {
    int p = tid >> 4, c = tid & 15;
    int pr = min(p0 + p, NPATHS - 1);
    float4 v = ps4[(size_t)pr * rs4 + c];
    hraw[p * 65 + c * 4 + 0] = v.x; hraw[p * 65 + c * 4 + 1] = v.y;
    hraw[p * 65 + c * 4 + 2] = v.z; hraw[p * 65 + c * 4 + 3] = v.w;
  }

  float acc[16];
#pragma unroll
  for (int j = 0; j < 16; ++j) acc[j] = b1[c0 + j];
  softbar();

  const uint32_t base = (uint32_t)(p0 + lane) * 256u + (uint32_t)c0;

#pragma unroll 4
  for (int k = 0; k < DD; ++k) {
    float pk = hraw[lane * 65 + k];
    const float* wp = &W1[k * 256 + c0];
#pragma unroll
    for (int j = 0; j < 16; ++j) acc[j] = fmaf(pk, wp[j], acc[j]);
  }
  softbar();

#pragma unroll
  for (int j = 0; j < 16; ++j) {
    float v = seluf_(acc[j]);
    bool keep = bern_keep(k1a, k1b, base + (uint32_t)j);
    hraw[lane * 257 + c0 + j] = keep ? v * 2.0f : 0.0f;
  }
  softbar();

#pragma unroll
  for (int j = 0; j < 16; ++j) acc[j] = b2[c0 + j];
#pragma unroll 4
  for (int k = 0; k < 256; ++k) {
    float hk = hraw[lane * 257 + k];
    const float* wp = &W2[k * 256 + c0];
#pragma unroll
    for (int j = 0; j < 16; ++j) acc[j] = fmaf(hk, wp[j], acc[j]);
  }

  {
    float s = 0.0f;
#pragma unroll
    for (int j = 0; j < 16; ++j) {
      float v = seluf_(acc[j]);
      bool keep = bern_keep(k2a, k2b, base + (uint32_t)j);
      float h2 = keep ? v * 2.0f : 0.0f;
      s = fmaf(h2, W3[c0 + j], s);
    }
    part_s[lane][w] = s;
  }
  softbar();

  if (w == 0) {
    float t = b3[0];
#pragma unroll
    for (int ww = 0; ww < 16; ++ww) t += part_s[lane][ww];
    if (p0 + lane < NPATHS) out[p0 + lane] = t > 0.0f ? t : 0.0f;
  }
}

// ---------------- host ----------------
extern "C" void kernel_launch(void* const* d_in, const int* in_sizes, int n_in,
                              void* d_out, int out_size, void* d_ws, size_t ws_size,
                              hipStream_t stream) {
  const float* cap     = (const float*)d_in[0];
  const float* traffic = (const float*)d_in[1];
  const int*   links   = (const int*)d_in[2];
  const float* pWx = (const float*)d_in[5];
  const float* pWh = (const float*)d_in[6];
  const float* pb  = (const float*)d_in[7];
  const float* eWx = (const float*)d_in[8];
  const float* eWh = (const float*)d_in[9];
  const float* eb  = (const float*)d_in[10];
  const float* W1  = (const float*)d_in[11];
  const float* b1  = (const float*)d_in[12];
  const float* W2  = (const float*)d_in[13];
  const float* b2  = (const float*)d_in[14];
  const float* W3  = (const float*)d_in[15];
  const float* b3  = (const float*)d_in[16];
  float* out = (float*)d_out;

  uint32_t k1a, k1b, k2a, k2b;
  threefry2x32(0u, 1u, 0u, 0u, k1a, k1b);
  threefry2x32(0u, 1u, 0u, 1u, k2a, k2b);

  const size_t n_link = (size_t)NLINKS * DD;
  const size_t n_seq  = (size_t)NPATHS * LSEQ * DD;
  const size_t n_gx   = (size_t)NLINKS * GW;

  float* link_state = (float*)d_ws;
  float* seq_h      = link_state + n_link;
  float* gx         = seq_h + n_seq;
  int*   counts     = (int*)(gx + n_gx);
  int*   row_start  = counts + NLINKS;
  int*   cursor     = row_start + NLINKS;
  int*   edges      = cursor + NLINKS;

  init_gather_kernel<<<(NLINKS * DD + 255) / 256, 256, 0, stream>>>(
      cap, traffic, link_state, seq_h, counts);
  csr_hist_kernel<<<(NEDGE + 255) / 256, 256, 0, stream>>>(links, counts);
  csr_scan_kernel<<<1, 1024, 0, stream>>>(counts, row_start, cursor);
  csr_fill_kernel<<<(NEDGE + 255) / 256, 256, 0, stream>>>(links, cursor, edges);

  gx_pack_kernel<<<NB, 1024, 0, stream>>>(link_state, pWx, pb, gx);

  for (int it = 0; it < TITER; ++it) {
    path_gru_v16_kernel<<<NB, 1024, 0, stream>>>(gx, seq_h, links, pWh);
    link_gru_v11_kernel<<<NB, 1024, 0, stream>>>(link_state, seq_h,
                                                 row_start, cursor, edges,
                                                 eWx, eWh, eb,
                                                 pWx, pb, gx);
  }
  mlp_v9_kernel<<<NB, 1024, 0, stream>>>(
      (const float4*)seq_h + 7 * 16, LSEQ * 16,
      W1, b1, W2, b2, W3, b3, out, k1a, k1b, k2a, k2b);
}

// Round 20
// 1394.042 us; speedup vs baseline: 1.0750x; 1.0750x over previous
//
#include <hip/hip_runtime.h>
#include <cstdint>

// Problem constants (fixed by setup_inputs()).
#define NLINKS 20000
#define NPATHS 20000
#define LSEQ   8
#define TITER  8
#define DD     64
#define GW     192          // 3*DD gate width
#define NEDGE  (NPATHS * LSEQ)        // 160000
#define NB     ((NPATHS + 63) / 64)   // 313 blocks of 64 rows

// Soft workgroup barrier: LDS-visibility only (lgkmcnt), NO vmcnt drain —
// global loads/stores stay in flight across it.
__device__ static inline void softbar() {
  asm volatile("s_waitcnt lgkmcnt(0)" ::: "memory");
  __builtin_amdgcn_s_barrier();
  asm volatile("" ::: "memory");
}

// ---------------- Threefry-2x32 (exact JAX semantics) ----------------
__host__ __device__ static inline uint32_t rotl32(uint32_t x, unsigned r) {
  return (x << r) | (x >> (32u - r));
}

__host__ __device__ static inline void threefry2x32(uint32_t k0, uint32_t k1,
                                                    uint32_t c0, uint32_t c1,
                                                    uint32_t& o0, uint32_t& o1) {
  uint32_t ks0 = k0, ks1 = k1, ks2 = k0 ^ k1 ^ 0x1BD11BDAu;
  uint32_t x0 = c0 + ks0, x1 = c1 + ks1;
#define TF_R(r) { x0 += x1; x1 = rotl32(x1, r); x1 ^= x0; }
  TF_R(13) TF_R(15) TF_R(26) TF_R(6)  x0 += ks1; x1 += ks2 + 1u;
  TF_R(17) TF_R(29) TF_R(16) TF_R(24) x0 += ks2; x1 += ks0 + 2u;
  TF_R(13) TF_R(15) TF_R(26) TF_R(6)  x0 += ks0; x1 += ks1 + 3u;
  TF_R(17) TF_R(29) TF_R(16) TF_R(24) x0 += ks1; x1 += ks2 + 4u;
  TF_R(13) TF_R(15) TF_R(26) TF_R(6)  x0 += ks2; x1 += ks0 + 5u;
#undef TF_R
  o0 = x0; o1 = x1;
}

// bernoulli(key, 0.5, (20000,256)), flattened element j.
// jax_threefry_partitionable=True: counter (0, j), bits = o0 ^ o1.
__device__ static inline bool bern_keep(uint32_t key0, uint32_t key1, uint32_t j) {
  uint32_t o0, o1;
  threefry2x32(key0, key1, 0u, j, o0, o1);
  uint32_t bits = o0 ^ o1;
  float u = __uint_as_float((bits >> 9) | 0x3f800000u) - 1.0f;
  return u < 0.5f;
}

// Fast gates: __expf -> v_exp_f32 (native); abs err ~1e-7 (verified round 18:
// absmax 1.2e-4 vs 3.05e-3 threshold).
__device__ static inline float sigmoidf_(float x) {
  return 1.0f / (1.0f + __expf(-x));
}
__device__ static inline float tanh_fast(float x) {
  // tanh(x) = 2*sigmoid(2x) - 1
  return 2.0f * sigmoidf_(2.0f * x) - 1.0f;
}
__device__ static inline float seluf_(float x) {
  const float sc = 1.0507009873554805f;
  const float al = 1.6732632423543772f;
  return x > 0.0f ? sc * x : sc * al * expm1f(x);
}

// ---------------- init + CSR build (round-12 verified) ----------------
__global__ void init_gather_kernel(const float* __restrict__ cap,
                                   const float* __restrict__ traffic,
                                   float* __restrict__ link_state,
                                   float* __restrict__ seq_h,
                                   int* __restrict__ counts) {
  int i = blockIdx.x * blockDim.x + threadIdx.x;
  if (i < NLINKS * DD)
    link_state[i] = ((i & 63) == 0) ? cap[i >> 6] : 0.0f;
  if (i < NPATHS * DD) {
    int p = i >> 6, j = i & 63;
    seq_h[(p * LSEQ + (LSEQ - 1)) * DD + j] = (j == 0) ? traffic[p] : 0.0f;
  }
  if (i < NLINKS) counts[i] = 0;
}

__global__ void csr_hist_kernel(const int* __restrict__ links,
                                int* __restrict__ counts) {
  int e = blockIdx.x * blockDim.x + threadIdx.x;
  if (e < NEDGE) atomicAdd(&counts[links[e]], 1);
}

__global__ __launch_bounds__(1024, 1) void csr_scan_kernel(
    const int* __restrict__ counts,
    int* __restrict__ row_start,
    int* __restrict__ cursor) {
  __shared__ int sc[1024];
  const int i = threadIdx.x;
  const int base = i * 20;
  int s = 0;
  for (int j = 0; j < 20; ++j) {
    int r = base + j;
    if (r < NLINKS) s += counts[r];
  }
  sc[i] = s;
  __syncthreads();
  for (int off = 1; off < 1024; off <<= 1) {
    int v = (i >= off) ? sc[i - off] : 0;
    __syncthreads();
    sc[i] += v;
    __syncthreads();
  }
  int run = sc[i] - s;
  for (int j = 0; j < 20; ++j) {
    int r = base + j;
    if (r < NLINKS) {
      row_start[r] = run;
      cursor[r] = run;
      run += counts[r];
    }
  }
}

__global__ void csr_fill_kernel(const int* __restrict__ links,
                                int* __restrict__ cursor,
                                int* __restrict__ edges) {
  int e = blockIdx.x * blockDim.x + threadIdx.x;
  if (e < NEDGE) {
    int l = links[e];
    int pos = atomicAdd(&cursor[l], 1);
    edges[pos] = e;
  }
}

// ============================================================================
// gx (PACKED layout): slice w of link l = cols {8w..8w+8} U {128+4w..128+4w+4}
// stored contiguously at gx[l*192 + 12w .. +12). Consumer (path_gru wave w)
// reads 48B contiguous. Initial fill from init link_state; 1024 thr/16 waves.
// ============================================================================
__global__ __launch_bounds__(1024, 2) void gx_pack_kernel(
    const float* __restrict__ link_state,
    const float* __restrict__ Wx,
    const float* __restrict__ bias,
    float* __restrict__ gx) {
  __shared__ float ls_s[64][65];

  const int tid  = threadIdx.x;
  const int lane = tid & 63;
  const int w    = __builtin_amdgcn_readfirstlane(tid >> 6);   // 0..15
  const int l0   = blockIdx.x * 64;

  {
    int p = tid >> 4, c = tid & 15;
    int lr = min(l0 + p, NLINKS - 1);
    float4 v = reinterpret_cast<const float4*>(link_state)[lr * 16 + c];
    ls_s[p][c * 4 + 0] = v.x; ls_s[p][c * 4 + 1] = v.y;
    ls_s[p][c * 4 + 2] = v.z; ls_s[p][c * 4 + 3] = v.w;
  }

  const int gA = w * 8;          // packed entries 0..7  = cols gA..gA+8
  const int gC = 128 + w * 4;    // packed entries 8..11 = cols gC..gC+4
  float ga[12];
#pragma unroll
  for (int jj = 0; jj < 8; ++jj) ga[jj] = bias[gA + jj];
#pragma unroll
  for (int jj = 0; jj < 4; ++jj) ga[8 + jj] = bias[gC + jj];
  softbar();

#pragma unroll 4
  for (int k = 0; k < DD; ++k) {
    float xk = ls_s[lane][k];
    const float* wA = &Wx[k * GW + gA];   // wave-uniform -> s_load
    const float* wC = &Wx[k * GW + gC];
#pragma unroll
    for (int jj = 0; jj < 8; ++jj) ga[jj] = fmaf(xk, wA[jj], ga[jj]);
#pragma unroll
    for (int jj = 0; jj < 4; ++jj) ga[8 + jj] = fmaf(xk, wC[jj], ga[8 + jj]);
  }

  if (l0 + lane < NLINKS) {
    float* dst = &gx[(size_t)(l0 + lane) * GW + w * 12];
#pragma unroll
    for (int s = 0; s < 3; ++s)
      reinterpret_cast<float4*>(dst)[s] =
          make_float4(ga[s * 4 + 0], ga[s * 4 + 1], ga[s * 4 + 2], ga[s * 4 + 3]);
  }
}

// ============================================================================
// path GRU v9p (round-18 verified: b32 LDS state, unroll 4, native-exp gates,
// packed gx reads). Reference GRU (Python precedence):
// hh = tanh(xh + (r*h) @ Wh[:,2D:]).
// ============================================================================
__global__ __launch_bounds__(1024, 8) void path_gru_v9_kernel(
    const float* __restrict__ gx,
    float* __restrict__ seq_h,
    const int* __restrict__ links,
    const float* __restrict__ Wh) {
  __shared__ float h_s[64][65];
  __shared__ float z_s[64][65];
  __shared__ float r_s[64][65];     // rh

  const int tid  = threadIdx.x;
  const int lane = tid & 63;
  const int w    = __builtin_amdgcn_readfirstlane(tid >> 6);   // 0..15
  const int p0   = blockIdx.x * 64;

  {
    int p = tid >> 4, c = tid & 15;
    int pr = min(p0 + p, NPATHS - 1);
    float4 v = reinterpret_cast<const float4*>(seq_h)[(pr * LSEQ + 7) * 16 + c];
    h_s[p][c * 4 + 0] = v.x; h_s[p][c * 4 + 1] = v.y;
    h_s[p][c * 4 + 2] = v.z; h_s[p][c * 4 + 3] = v.w;
  }

  const int ab0 = w * 8;          // gate col base: z for w<8, r for w>=8
  const int cc0 = 128 + w * 4;    // cand col base
  const int hc0 = w * 4;          // h-update col base
  const int prow = min(p0 + lane, NPATHS - 1);
  const float4* gx4 = reinterpret_cast<const float4*>(gx);

  // gathers for t=0: packed slice = 3 consecutive float4
  float4 gz0, gz1, gc0;
  {
    int li = links[prow * LSEQ + 0];
    const float4* g = gx4 + (size_t)li * 48 + w * 3;
    gz0 = g[0]; gz1 = g[1]; gc0 = g[2];
  }
  softbar();   // h ready

  for (int t = 0; t < LSEQ; ++t) {
    // store out(t-1) = current h (stable through phase 1); 1 float4/thread
    if (t > 0) {
      int p = tid >> 4, c = tid & 15;
      if (p0 + p < NPATHS) {
        float4 v = make_float4(h_s[p][c * 4 + 0], h_s[p][c * 4 + 1],
                               h_s[p][c * 4 + 2], h_s[p][c * 4 + 3]);
        reinterpret_cast<float4*>(seq_h)[((p0 + p) * LSEQ + (t - 1)) * 16 + c] = v;
      }
    }

    // phase 1: aB = h @ Wh[:, ab0..ab0+8)  (weights: scalar loads)
    float aB[8];
#pragma unroll
    for (int jj = 0; jj < 8; ++jj) aB[jj] = 0.0f;
#pragma unroll 4
    for (int k = 0; k < DD; ++k) {
      float hk = h_s[lane][k];
      const float* whp = &Wh[k * GW + ab0];   // wave-uniform -> s_load
#pragma unroll
      for (int jj = 0; jj < 8; ++jj)
        aB[jj] = fmaf(hk, whp[jj], aB[jj]);
    }

    // gate write (consumes gz; compiler inserts the vmcnt wait right here)
    float gzf[8] = {gz0.x, gz0.y, gz0.z, gz0.w, gz1.x, gz1.y, gz1.z, gz1.w};
    if (w < 8) {
#pragma unroll
      for (int jj = 0; jj < 8; ++jj)
        z_s[lane][ab0 + jj] = sigmoidf_(gzf[jj] + aB[jj]);           // z
    } else {
#pragma unroll
      for (int jj = 0; jj < 8; ++jj) {
        int hj = ab0 - 64 + jj;
        float r = sigmoidf_(gzf[jj] + aB[jj]);
        r_s[lane][hj] = r * h_s[lane][hj];                            // rh
      }
    }
    softbar();  // BAR1: z/rh visible; phase-1 h reads done

    // phase 2
    int li_n = (t < LSEQ - 1) ? links[prow * LSEQ + t + 1] : 0;

    float aC[4];
#pragma unroll
    for (int jj = 0; jj < 4; ++jj) aC[jj] = 0.0f;
#pragma unroll 4
    for (int k = 0; k < DD; ++k) {
      float rhk = r_s[lane][k];
      const float* whc = &Wh[k * GW + cc0];   // wave-uniform -> s_load
#pragma unroll
      for (int jj = 0; jj < 4; ++jj)
        aC[jj] = fmaf(rhk, whc[jj], aC[jj]);
    }
    float gcf[4] = {gc0.x, gc0.y, gc0.z, gc0.w};
#pragma unroll
    for (int jj = 0; jj < 4; ++jj) {
      int j = hc0 + jj;
      float z    = z_s[lane][j];
      float hold = h_s[lane][j];
      float hh = tanh_fast(gcf[jj] + aC[jj]);
      h_s[lane][j] = z * hold + (1.0f - z) * hh;
    }

    // issue gathers for t+1 AFTER last use of gz/gc; they stay in flight
    // across BAR2 + next phase 1 (soft barrier: no vmcnt drain).
    if (t < LSEQ - 1) {
      const float4* g = gx4 + (size_t)li_n * 48 + w * 3;
      gz0 = g[0]; gz1 = g[1]; gc0 = g[2];
    }
    softbar();  // BAR2: h updated; z/r free
  }

  // final store: out(7) -> seq row 7 (carried state)
  {
    int p = tid >> 4, c = tid & 15;
    if (p0 + p < NPATHS) {
      float4 v = make_float4(h_s[p][c * 4 + 0], h_s[p][c * 4 + 1],
                             h_s[p][c * 4 + 2], h_s[p][c * 4 + 3]);
      reinterpret_cast<float4*>(seq_h)[((p0 + p) * LSEQ + 7) * 16 + c] = v;
    }
  }
}

// ============================================================================
// link GRU v11p (round-18 verified: unroll 4, native-exp gates, fused PACKED
// gx tail).
// ============================================================================
__global__ __launch_bounds__(1024, 8) void link_gru_v11_kernel(
    float* __restrict__ link_state,
    const float* __restrict__ seq_h,
    const int* __restrict__ row_start,
    const int* __restrict__ row_end,
    const int* __restrict__ edges,
    const float* __restrict__ Wx,
    const float* __restrict__ Wh,
    const float* __restrict__ bias,
    const float* __restrict__ pWx,
    const float* __restrict__ pb,
    float* __restrict__ gx_out) {
  __shared__ float h_s[64][65];
  __shared__ float x_s[64][65];
  __shared__ float r_s[64][65];

  const int tid  = threadIdx.x;
  const int lane = tid & 63;
  const int w    = __builtin_amdgcn_readfirstlane(tid >> 6);   // 0..15
  const int l0   = blockIdx.x * 64;

  {
    int p = tid >> 4, c = tid & 15;
    float4 hv = make_float4(0.f, 0.f, 0.f, 0.f);
    float4 xv = make_float4(0.f, 0.f, 0.f, 0.f);
    if (l0 + p < NLINKS) {
      hv = reinterpret_cast<const float4*>(link_state)[(l0 + p) * 16 + c];
      const float4* s4 = reinterpret_cast<const float4*>(seq_h);
      int rs = row_start[l0 + p], re = row_end[l0 + p];
      int ii = rs;
      for (; ii + 4 <= re; ii += 4) {
        int e0 = edges[ii + 0], e1 = edges[ii + 1];
        int e2 = edges[ii + 2], e3 = edges[ii + 3];
        float4 v0 = s4[e0 * 16 + c], v1 = s4[e1 * 16 + c];
        float4 v2 = s4[e2 * 16 + c], v3 = s4[e3 * 16 + c];
        xv.x += v0.x + v1.x + v2.x + v3.x;
        xv.y += v0.y + v1.y + v2.y + v3.y;
        xv.z += v0.z + v1.z + v2.z + v3.z;
        xv.w += v0.w + v1.w + v2.w + v3.w;
      }
      for (; ii < re; ++ii) {
        int e = edges[ii];
        float4 v = s4[e * 16 + c];
        xv.x += v.x; xv.y += v.y; xv.z += v.z; xv.w += v.w;
      }
    }
    h_s[p][c * 4 + 0] = hv.x; h_s[p][c * 4 + 1] = hv.y;
    h_s[p][c * 4 + 2] = hv.z; h_s[p][c * 4 + 3] = hv.w;
    x_s[p][c * 4 + 0] = xv.x; x_s[p][c * 4 + 1] = xv.y;
    x_s[p][c * 4 + 2] = xv.z; x_s[p][c * 4 + 3] = xv.w;
  }

  const int ab0 = w * 8;
  const int cc0 = 128 + w * 4;
  const int hc0 = w * 4;

  float bab[8], bcc[4];
#pragma unroll
  for (int jj = 0; jj < 8; ++jj) bab[jj] = bias[ab0 + jj];
#pragma unroll
  for (int jj = 0; jj < 4; ++jj) bcc[jj] = bias[cc0 + jj];

  softbar();

  // phase 1: aA = x@Wx, aB = h@Wh (8 cols), cA = x@Wx cand (4 cols)
  float aA[8], aB[8], cA[4];
#pragma unroll
  for (int jj = 0; jj < 8; ++jj) { aA[jj] = bab[jj]; aB[jj] = 0.0f; }
#pragma unroll
  for (int jj = 0; jj < 4; ++jj) cA[jj] = bcc[jj];
#pragma unroll 4
  for (int k = 0; k < DD; ++k) {
    float xk = x_s[lane][k];
    float hk = h_s[lane][k];
    const float* wxp = &Wx[k * GW + ab0];   // wave-uniform -> s_load
    const float* whp = &Wh[k * GW + ab0];
    const float* wxc = &Wx[k * GW + cc0];
#pragma unroll
    for (int jj = 0; jj < 8; ++jj) {
      aA[jj] = fmaf(xk, wxp[jj], aA[jj]);
      aB[jj] = fmaf(hk, whp[jj], aB[jj]);
    }
#pragma unroll
    for (int jj = 0; jj < 4; ++jj)
      cA[jj] = fmaf(xk, wxc[jj], cA[jj]);
  }
  softbar();  // all waves' x_s reads complete before z overwrites x_s

  if (w < 8) {
#pragma unroll
    for (int jj = 0; jj < 8; ++jj)
      x_s[lane][ab0 + jj] = sigmoidf_(aA[jj] + aB[jj]);   // z (reuse x_s)
  } else {
#pragma unroll
    for (int jj = 0; jj < 8; ++jj) {
      int hj = ab0 - 64 + jj;
      float r = sigmoidf_(aA[jj] + aB[jj]);
      r_s[lane][hj] = r * h_s[lane][hj];
    }
  }
  softbar();

  // phase 2
  float aC[4];
#pragma unroll
  for (int jj = 0; jj < 4; ++jj) aC[jj] = 0.0f;
#pragma unroll 4
  for (int k = 0; k < DD; ++k) {
    float rhk = r_s[lane][k];
    const float* whc = &Wh[k * GW + cc0];   // wave-uniform -> s_load
#pragma unroll
    for (int jj = 0; jj < 4; ++jj)
      aC[jj] = fmaf(rhk, whc[jj], aC[jj]);
  }
  {
    float o[4];
#pragma unroll
    for (int jj = 0; jj < 4; ++jj) {
      int j = hc0 + jj;
      float z    = x_s[lane][j];
      float hold = h_s[lane][j];
      float hh = tanh_fast(cA[jj] + aC[jj]);
      o[jj] = z * hold + (1.0f - z) * hh;
      x_s[lane][j] = o[jj];    // own-wave col: z read above, now h_new
    }
    if (l0 + lane < NLINKS) {
      reinterpret_cast<float4*>(&link_state[(size_t)(l0 + lane) * DD + hc0])[0]
          = make_float4(o[0], o[1], o[2], o[3]);
    }
  }
  softbar();  // h_new (all 64 cols) visible in x_s

  // fused gx production (PACKED): slice w = cols {8w..8w+8} U {128+4w..+4},
  // stored at gx_out[l*192 + 12w .. +12).
  {
    const int gA = w * 8;
    const int gC = 128 + w * 4;
    float ga[12];
#pragma unroll
    for (int jj = 0; jj < 8; ++jj) ga[jj] = pb[gA + jj];
#pragma unroll
    for (int jj = 0; jj < 4; ++jj) ga[8 + jj] = pb[gC + jj];
#pragma unroll 4
    for (int k = 0; k < DD; ++k) {
      float hk = x_s[lane][k];
      const float* wA = &pWx[k * GW + gA];   // wave-uniform -> s_load
      const float* wC = &pWx[k * GW + gC];
#pragma unroll
      for (int jj = 0; jj < 8; ++jj) ga[jj] = fmaf(hk, wA[jj], ga[jj]);
#pragma unroll
      for (int jj = 0; jj < 4; ++jj) ga[8 + jj] = fmaf(hk, wC[jj], ga[8 + jj]);
    }
    if (l0 + lane < NLINKS) {
      float* dst = &gx_out[(size_t)(l0 + lane) * GW + w * 12];
#pragma unroll
      for (int s = 0; s < 3; ++s)
        reinterpret_cast<float4*>(dst)[s] =
            make_float4(ga[s * 4 + 0], ga[s * 4 + 1], ga[s * 4 + 2], ga[s * 4 + 3]);
    }
  }
}

// ============================================================================
// MLP v9 (round-12 verified): ps overlay in hbuf, 70 KB LDS -> 2 blocks/CU.
// Lane = path; wave w owns cols [16w,16w+16); scalar-pipe weights.
// ============================================================================
__global__ __launch_bounds__(1024, 8) void mlp_v9_kernel(
    const float4* __restrict__ ps4, int rs4,
    const float* __restrict__ W1, const float* __restrict__ b1,
    const float* __restrict__ W2, const float* __restrict__ b2,
    const float* __restrict__ W3, const float* __restrict__ b3,
    float* __restrict__ out,
    uint32_t k1a, uint32_t k1b, uint32_t k2a, uint32_t k2b) {
  __shared__ float hraw[64 * 257];   // 65.8 KB; first 64*65 floats double as ps
  __shared__ float part_s[64][17];   //  4.4 KB

  const int tid  = threadIdx.x;
  const int lane = tid & 63;
  const int w    = __builtin_amdgcn_readfirstlane(tid >> 6);   // 0..15
  const int p0   = blockIdx.x * 64;
  const int c0   = w * 16;

  {
    int p = tid >> 4, c = tid & 15;
    int pr = min(p0 + p, NPATHS - 1);
    float4 v = ps4[(size_t)pr * rs4 + c];
    hraw[p * 65 + c * 4 + 0] = v.x; hraw[p * 65 + c * 4 + 1] = v.y;
    hraw[p * 65 + c * 4 + 2] = v.z; hraw[p * 65 + c * 4 + 3] = v.w;
  }

  float acc[16];
#pragma unroll
  for (int j = 0; j < 16; ++j) acc[j] = b1[c0 + j];
  softbar();   // ps staged

  const uint32_t base = (uint32_t)(p0 + lane) * 256u + (uint32_t)c0;

#pragma unroll 4
  for (int k = 0; k < DD; ++k) {
    float pk = hraw[lane * 65 + k];
    const float* wp = &W1[k * 256 + c0];
#pragma unroll
    for (int j = 0; j < 16; ++j) acc[j] = fmaf(pk, wp[j], acc[j]);
  }
  softbar();   // ALL ps reads done before hbuf overwrites the overlay region

#pragma unroll
  for (int j = 0; j < 16; ++j) {
    float v = seluf_(acc[j]);
    bool keep = bern_keep(k1a, k1b, base + (uint32_t)j);
    hraw[lane * 257 + c0 + j] = keep ? v * 2.0f : 0.0f;
  }
  softbar();   // h1 ready

#pragma unroll
  for (int j = 0; j < 16; ++j) acc[j] = b2[c0 + j];
#pragma unroll 4
  for (int k = 0; k < 256; ++k) {
    float hk = hraw[lane * 257 + k];
    const float* wp = &W2[k * 256 + c0];
#pragma unroll
    for (int j = 0; j < 16; ++j) acc[j] = fmaf(hk, wp[j], acc[j]);
  }

  {
    float s = 0.0f;
#pragma unroll
    for (int j = 0; j < 16; ++j) {
      float v = seluf_(acc[j]);
      bool keep = bern_keep(k2a, k2b, base + (uint32_t)j);
      float h2 = keep ? v * 2.0f : 0.0f;
      s = fmaf(h2, W3[c0 + j], s);
    }
    part_s[lane][w] = s;
  }
  softbar();

  if (w == 0) {
    float t = b3[0];
#pragma unroll
    for (int ww = 0; ww < 16; ++ww) t += part_s[lane][ww];
    if (p0 + lane < NPATHS) out[p0 + lane] = t > 0.0f ? t : 0.0f;
  }
}

// ---------------- host ----------------
extern "C" void kernel_launch(void* const* d_in, const int* in_sizes, int n_in,
                              void* d_out, int out_size, void* d_ws, size_t ws_size,
                              hipStream_t stream) {
  const float* cap     = (const float*)d_in[0];
  const float* traffic = (const float*)d_in[1];
  const int*   links   = (const int*)d_in[2];
  const float* pWx = (const float*)d_in[5];
  const float* pWh = (const float*)d_in[6];
  const float* pb  = (const float*)d_in[7];
  const float* eWx = (const float*)d_in[8];
  const float* eWh = (const float*)d_in[9];
  const float* eb  = (const float*)d_in[10];
  const float* W1  = (const float*)d_in[11];
  const float* b1  = (const float*)d_in[12];
  const float* W2  = (const float*)d_in[13];
  const float* b2  = (const float*)d_in[14];
  const float* W3  = (const float*)d_in[15];
  const float* b3  = (const float*)d_in[16];
  float* out = (float*)d_out;

  uint32_t k1a, k1b, k2a, k2b;
  threefry2x32(0u, 1u, 0u, 0u, k1a, k1b);
  threefry2x32(0u, 1u, 0u, 1u, k2a, k2b);

  const size_t n_link = (size_t)NLINKS * DD;
  const size_t n_seq  = (size_t)NPATHS * LSEQ * DD;
  const size_t n_gx   = (size_t)NLINKS * GW;

  float* link_state = (float*)d_ws;
  float* seq_h      = link_state + n_link;
  float* gx         = seq_h + n_seq;
  int*   counts     = (int*)(gx + n_gx);
  int*   row_start  = counts + NLINKS;
  int*   cursor     = row_start + NLINKS;
  int*   edges      = cursor + NLINKS;

  init_gather_kernel<<<(NLINKS * DD + 255) / 256, 256, 0, stream>>>(
      cap, traffic, link_state, seq_h, counts);
  csr_hist_kernel<<<(NEDGE + 255) / 256, 256, 0, stream>>>(links, counts);
  csr_scan_kernel<<<1, 1024, 0, stream>>>(counts, row_start, cursor);
  csr_fill_kernel<<<(NEDGE + 255) / 256, 256, 0, stream>>>(links, cursor, edges);

  // initial gx (packed) from the init link_state; thereafter link_gru
  // produces it in the same packed layout.
  gx_pack_kernel<<<NB, 1024, 0, stream>>>(link_state, pWx, pb, gx);

  for (int it = 0; it < TITER; ++it) {
    path_gru_v9_kernel<<<NB, 1024, 0, stream>>>(gx, seq_h, links, pWh);
    link_gru_v11_kernel<<<NB, 1024, 0, stream>>>(link_state, seq_h,
                                                 row_start, cursor, edges,
                                                 eWx, eWh, eb,
                                                 pWx, pb, gx);
  }
  mlp_v9_kernel<<<NB, 1024, 0, stream>>>(
      (const float4*)seq_h + 7 * 16, LSEQ * 16,
      W1, b1, W2, b2, W3, b3, out, k1a, k1b, k2a, k2b);
}